// Round 1
// baseline (542.632 us; speedup 1.0000x reference)
//
#include <hip/hip_runtime.h>
#include <hip/hip_fp16.h>

static constexpr float KEHALF = 7.199822675975274f; // 14.399645351950548 / 2
static constexpr int APB = 2048;          // atoms per bucket (8 KB acc tile)
static constexpr int APB_SHIFT = 11;
static constexpr int NBMAX = 256;         // scan width (pow2); NB <= this
static constexpr int CHUNK = 8192;        // pairs per Phase-A block
static constexpr int ABLK = 512;          // Phase-A block size
static constexpr int BBLK = 1024;         // Phase-B block size
static constexpr int CTILE = 1024;        // Phase-B chunk-range staging tile
static constexpr int NW_SCAN = NBMAX / 64;

typedef float v4f __attribute__((ext_vector_type(4)));
typedef int   v4i __attribute__((ext_vector_type(4)));
typedef unsigned v4u __attribute__((ext_vector_type(4)));

// ---------------------------------------------------------------------------
// consts [0]=sp(apow) [1]=sp(adiv) [2..5]=c1n..c4n [6..9]=sp(a1..a4)
// ---------------------------------------------------------------------------
__global__ void zbl_tables_kernel(const float* __restrict__ adiv,
                                  const float* __restrict__ apow,
                                  const float* __restrict__ c1,
                                  const float* __restrict__ c2,
                                  const float* __restrict__ c3,
                                  const float* __restrict__ c4,
                                  const float* __restrict__ a1,
                                  const float* __restrict__ a2,
                                  const float* __restrict__ a3,
                                  const float* __restrict__ a4,
                                  float* __restrict__ consts) {
    if (threadIdx.x == 0) {
        auto sp = [](float x) { return log1pf(expf(x)); };
        float c1p = sp(*c1), c2p = sp(*c2), c3p = sp(*c3), c4p = sp(*c4);
        float inv = 1.0f / (c1p + c2p + c3p + c4p);
        consts[0] = sp(*apow);
        consts[1] = sp(*adiv);
        consts[2] = c1p * inv; consts[3] = c2p * inv;
        consts[4] = c3p * inv; consts[5] = c4p * inv;
        consts[6] = sp(*a1); consts[7] = sp(*a2);
        consts[8] = sp(*a3); consts[9] = sp(*a4);
    }
}

// ---------------------------------------------------------------------------
// zb[i] = (u8)Zf[i] — 500 KB gather table (L2-resident)
// ---------------------------------------------------------------------------
__global__ void zbl_pack_kernel(const float* __restrict__ Zf,
                                unsigned char* __restrict__ zb, int N) {
    int i = blockIdx.x * blockDim.x + threadIdx.x;
    if (i < N) zb[i] = (unsigned char)(Zf[i] + 0.5f);
}

// ---------------------------------------------------------------------------
// Phase A: per-chunk counting sort. Records are 4 B: [idx_local:16|f16:16].
// LDS-minimal version: idx_i held in registers across the scan, z^p computed
// in VALU (no lA table), records scatter-stored directly to the chunk's
// 32 KB global window (L2 absorbs; no LDS stage+flush phase).
// ---------------------------------------------------------------------------
__global__ void __launch_bounds__(ABLK)
zbl_phaseA(const int* __restrict__ idx_i, const int* __restrict__ idx_j,
           const float* __restrict__ rij, const float* __restrict__ cut,
           const unsigned char* __restrict__ zb,
           const float* __restrict__ consts,
           unsigned* __restrict__ recs, unsigned short* __restrict__ starts,
           int P, int NB) {
    __shared__ unsigned hist[NBMAX];
    __shared__ unsigned cursor[NBMAX];
    __shared__ unsigned wsum[NW_SCAN];

    const int t = threadIdx.x;
    const int c = blockIdx.x;
    const int base = c * CHUNK;
    const int lim = min(base + CHUNK, P);
    const int cnt = lim - base;
    const int n4 = cnt >> 2;

    for (int b = t; b < NBMAX; b += ABLK) hist[b] = 0;
    __syncthreads();

    // ---- pass 1: load idx_i into registers, histogram from registers
    const v4i* ii4 = reinterpret_cast<const v4i*>(idx_i + base);
    const bool p0 = t < n4;
    const bool p1 = ABLK + t < n4;
    const bool p2 = 2 * ABLK + t < n4;
    const bool p3 = 3 * ABLK + t < n4;
    v4i ii0{}, ii1{}, ii2{}, ii3{};
    if (p0) ii0 = __builtin_nontemporal_load(ii4 + t);
    if (p1) ii1 = __builtin_nontemporal_load(ii4 + ABLK + t);
    if (p2) ii2 = __builtin_nontemporal_load(ii4 + 2 * ABLK + t);
    if (p3) ii3 = __builtin_nontemporal_load(ii4 + 3 * ABLK + t);

    auto hist4 = [&](v4i ii) {
        atomicAdd(&hist[(unsigned)ii[0] >> APB_SHIFT], 1u);
        atomicAdd(&hist[(unsigned)ii[1] >> APB_SHIFT], 1u);
        atomicAdd(&hist[(unsigned)ii[2] >> APB_SHIFT], 1u);
        atomicAdd(&hist[(unsigned)ii[3] >> APB_SHIFT], 1u);
    };
    if (p0) hist4(ii0);
    if (p1) hist4(ii1);
    if (p2) hist4(ii2);
    if (p3) hist4(ii3);
    for (int p = n4 * 4 + t; p < cnt; p += ABLK)
        atomicAdd(&hist[(unsigned)idx_i[base + p] >> APB_SHIFT], 1u);
    __syncthreads();

    // ---- shuffle-based inclusive scan (2 barriers instead of 16)
    unsigned hv = (t < NBMAX) ? hist[t] : 0u;
    unsigned v = hv;
#pragma unroll
    for (int off = 1; off < 64; off <<= 1) {
        unsigned n = __shfl_up(v, off, 64);
        if ((t & 63) >= off) v += n;
    }
    if (t < NBMAX && (t & 63) == 63) wsum[t >> 6] = v;
    __syncthreads();
    const int S = NB + 1;
    if (t < NBMAX) {
        unsigned pre = 0;
#pragma unroll
        for (int w = 0; w < NW_SCAN - 1; ++w)
            if (w < (t >> 6)) pre += wsum[w];
        unsigned inc = v + pre;           // inclusive scan of hist
        cursor[t] = inc - hv;             // exclusive base
        if (t < NB)
            starts[(size_t)c * S + t + 1] = (unsigned short)inc;
    }
    if (t == 0) starts[(size_t)c * S] = 0;
    __syncthreads();                      // cursor visible to all waves

    // ---- pass 2: compute + rank + direct scatter store (32 KB L2 window)
    const float sp_apow = consts[0], sp_adiv = consts[1];
    const float c1n = consts[2], c2n = consts[3], c3n = consts[4], c4n = consts[5];
    const float a1 = consts[6], a2 = consts[7], a3 = consts[8], a4 = consts[9];

    auto process = [&](int i, int j, float r, float cu) {
        unsigned bi = zb[i], bj = zb[j];
        float fi = (float)bi, fj = (float)bj;
        float zi = __expf(sp_apow * __logf(fi));
        float zj = __expf(sp_apow * __logf(fj));
        float ar = (zi + zj) * sp_adiv * r;
        float f = c1n * __expf(-a1 * ar) + c2n * __expf(-a2 * ar)
                + c3n * __expf(-a3 * ar) + c4n * __expf(-a4 * ar);
        float contrib = KEHALF * f * cu * fi * fj * __builtin_amdgcn_rcpf(r);
        unsigned b = (unsigned)i >> APB_SHIFT;
        unsigned rank = atomicAdd(&cursor[b], 1u);
        unsigned rec = (((unsigned)i & (APB - 1)) << 16)
                     | (unsigned)__half_as_ushort(__float2half_rn(contrib));
        recs[(size_t)base + rank] = rec;  // cached store; L2 write-combines
    };

    const v4i* jj4 = reinterpret_cast<const v4i*>(idx_j + base);
    const v4f* rr4 = reinterpret_cast<const v4f*>(rij + base);
    const v4f* cc4 = reinterpret_cast<const v4f*>(cut + base);
    auto group = [&](v4i ii, int q) {
        v4i jj = __builtin_nontemporal_load(jj4 + q);
        v4f rr = __builtin_nontemporal_load(rr4 + q);
        v4f cc = __builtin_nontemporal_load(cc4 + q);
#pragma unroll
        for (int k = 0; k < 4; ++k) process(ii[k], jj[k], rr[k], cc[k]);
    };
    if (p0) group(ii0, t);
    if (p1) group(ii1, ABLK + t);
    if (p2) group(ii2, 2 * ABLK + t);
    if (p3) group(ii3, 3 * ABLK + t);
    for (int p = n4 * 4 + t; p < cnt; p += ABLK)
        process(idx_i[base + p], idx_j[base + p], rij[base + p], cut[base + p]);
}

// ---------------------------------------------------------------------------
// Phase B: grid (NB, SPLIT). Each block owns one bucket x one chunk slice;
// half-wave (32 lanes) per chunk segment; ds-atomic into 8 KB tile; merge
// into out via f32 atomics (out pre-zeroed).
// ---------------------------------------------------------------------------
__global__ void __launch_bounds__(BBLK)
zbl_phaseB(const unsigned* __restrict__ recs,
           const unsigned short* __restrict__ starts,
           float* __restrict__ out, int N, int NB, int nchunks, int cpb) {
    __shared__ float acc[APB];                 // 8 KB
    __shared__ unsigned short s0s[CTILE];      // 2 KB
    __shared__ unsigned short s1s[CTILE];      // 2 KB
    const int t = threadIdx.x;
    const int b = blockIdx.x;
    const int c0 = blockIdx.y * cpb;
    const int c1e = min(c0 + cpb, nchunks);
    const int S = NB + 1;
    for (int i = t; i < APB; i += BBLK) acc[i] = 0.f;

    const int hw = t >> 5, hl = t & 31, nhw = BBLK / 32;

    for (int cb = c0; cb < c1e; cb += CTILE) {
        const int ce = min(cb + CTILE, c1e);
        __syncthreads();
        for (int c = cb + t; c < ce; c += BBLK) {
            s0s[c - cb] = starts[(size_t)c * S + b];
            s1s[c - cb] = starts[(size_t)c * S + b + 1];
        }
        __syncthreads();
        for (int c = cb + hw; c < ce; c += nhw) {
            unsigned s0 = s0s[c - cb], s1 = s1s[c - cb];
            const unsigned* seg = recs + (size_t)c * CHUNK;
            for (unsigned u = s0 + hl; u < s1; u += 32) {
                unsigned rec = __builtin_nontemporal_load(seg + u);
                float v = __half2float(__ushort_as_half((unsigned short)(rec & 0xffffu)));
                atomicAdd(&acc[rec >> 16], v);
            }
        }
    }
    __syncthreads();
    const int abase = b << APB_SHIFT;
    for (int i = t; i < APB; i += BBLK) {
        int g = abase + i;
        if (g < N) atomicAdd(&out[g], acc[i]);
    }
}

// ---------------------------------------------------------------------------
// Fallback (tiny ws): direct device-scope atomics.
// ---------------------------------------------------------------------------
__global__ void __launch_bounds__(256)
zbl_pair_fallback(const v4f* __restrict__ rij4, const v4f* __restrict__ cut4,
                  const v4i* __restrict__ ii4, const v4i* __restrict__ jj4,
                  const float* __restrict__ Zf, const float* __restrict__ consts,
                  float* __restrict__ out, int P4) {
    int t = blockIdx.x * blockDim.x + threadIdx.x;
    if (t >= P4) return;
    const float sp_apow = consts[0], sp_adiv = consts[1];
    const float c1n = consts[2], c2n = consts[3], c3n = consts[4], c4n = consts[5];
    const float a1 = consts[6], a2 = consts[7], a3 = consts[8], a4 = consts[9];
    v4f rr = rij4[t]; v4f cc = cut4[t]; v4i ii = ii4[t]; v4i jj = jj4[t];
#pragma unroll
    for (int k = 0; k < 4; ++k) {
        int i = ii[k], j = jj[k];
        float zfi = Zf[i], zfj = Zf[j];
        float zi = __expf(sp_apow * __logf(zfi));
        float zj = __expf(sp_apow * __logf(zfj));
        float a = (zi + zj) * sp_adiv;
        float ar = a * rr[k];
        float f = c1n * __expf(-a1 * ar) + c2n * __expf(-a2 * ar)
                + c3n * __expf(-a3 * ar) + c4n * __expf(-a4 * ar);
        atomicAdd(&out[i],
                  KEHALF * f * cc[k] * zfi * zfj * __builtin_amdgcn_rcpf(rr[k]));
    }
}

// ---------------------------------------------------------------------------
extern "C" void kernel_launch(void* const* d_in, const int* in_sizes, int n_in,
                              void* d_out, int out_size, void* d_ws, size_t ws_size,
                              hipStream_t stream) {
    // 0:N 1:Zf 2:rij 3:cutoff 4:idx_i 5:idx_j 6:adiv 7:apow 8..11:c 12..15:a
    const float* Zf = (const float*)d_in[1];
    const float* rij = (const float*)d_in[2];
    const float* cut = (const float*)d_in[3];
    const int* idx_i = (const int*)d_in[4];
    const int* idx_j = (const int*)d_in[5];
    const int N = in_sizes[1];
    const int P = in_sizes[2];
    float* out = (float*)d_out;

    const int NB = (N + APB - 1) / APB;
    const int nchunks = (P + CHUNK - 1) / CHUNK;

    // ws layout: recs[nchunks*CHUNK] u32 | starts[nchunks*(NB+1)] u16 |
    //            consts[16] f32 | zb[N] u8
    size_t recs_bytes = (size_t)nchunks * CHUNK * 4;
    size_t starts_bytes = (size_t)nchunks * (NB + 1) * 2;
    size_t consts_off = (recs_bytes + starts_bytes + 255) & ~(size_t)255;
    size_t zb_off = consts_off + 16 * 4;
    size_t need = zb_off + (size_t)N + 64;

    if (NB <= NBMAX && ws_size >= need) {
        unsigned* recs = (unsigned*)d_ws;
        unsigned short* starts = (unsigned short*)((char*)d_ws + recs_bytes);
        float* consts = (float*)((char*)d_ws + consts_off);
        unsigned char* zb = (unsigned char*)((char*)d_ws + zb_off);

        zbl_tables_kernel<<<1, 64, 0, stream>>>(
            (const float*)d_in[6], (const float*)d_in[7],
            (const float*)d_in[8], (const float*)d_in[9],
            (const float*)d_in[10], (const float*)d_in[11],
            (const float*)d_in[12], (const float*)d_in[13],
            (const float*)d_in[14], (const float*)d_in[15], consts);

        zbl_pack_kernel<<<(N + 255) / 256, 256, 0, stream>>>(Zf, zb, N);

        hipMemsetAsync(out, 0, (size_t)out_size * sizeof(float), stream);

        zbl_phaseA<<<nchunks, ABLK, 0, stream>>>(
            idx_i, idx_j, rij, cut, zb, consts, recs, starts, P, NB);

        int SPLIT = (2048 + NB - 1) / NB;
        if (SPLIT < 1) SPLIT = 1;
        if (SPLIT > 16) SPLIT = 16;
        const int cpb = (nchunks + SPLIT - 1) / SPLIT;
        dim3 gridB(NB, SPLIT);
        zbl_phaseB<<<gridB, BBLK, 0, stream>>>(recs, starts, out, N, NB,
                                               nchunks, cpb);
    } else {
        float* consts = (float*)d_ws;
        hipMemsetAsync(out, 0, (size_t)out_size * sizeof(float), stream);
        zbl_tables_kernel<<<1, 64, 0, stream>>>(
            (const float*)d_in[6], (const float*)d_in[7],
            (const float*)d_in[8], (const float*)d_in[9],
            (const float*)d_in[10], (const float*)d_in[11],
            (const float*)d_in[12], (const float*)d_in[13],
            (const float*)d_in[14], (const float*)d_in[15], consts);
        zbl_pair_fallback<<<(P / 4 + 255) / 256, 256, 0, stream>>>(
            (const v4f*)rij, (const v4f*)cut, (const v4i*)idx_i,
            (const v4i*)idx_j, Zf, consts, out, P / 4);
    }
}

// Round 2
// 453.738 us; speedup vs baseline: 1.1959x; 1.1959x over previous
//
#include <hip/hip_runtime.h>
#include <hip/hip_fp16.h>

static constexpr float KEHALF = 7.199822675975274f; // 14.399645351950548 / 2
static constexpr int APB = 2048;          // atoms per bucket (8 KB acc tile)
static constexpr int APB_SHIFT = 11;
static constexpr int NBMAX = 256;         // scan width (pow2); NB <= this
static constexpr int CHUNK = 8192;        // pairs per Phase-A block (32 KB stage)
static constexpr int ABLK = 512;          // Phase-A block size
static constexpr int BBLK = 1024;         // Phase-B block size
static constexpr int CTILE = 1024;        // Phase-B chunk-range staging tile
static constexpr int NW_SCAN = NBMAX / 64;

typedef float v4f __attribute__((ext_vector_type(4)));
typedef int   v4i __attribute__((ext_vector_type(4)));
typedef unsigned v4u __attribute__((ext_vector_type(4)));

// ---------------------------------------------------------------------------
// consts [0]=sp(apow) [1]=sp(adiv) [2..5]=c1n..c4n [6..9]=sp(a1..a4)
// ---------------------------------------------------------------------------
__global__ void zbl_tables_kernel(const float* __restrict__ adiv,
                                  const float* __restrict__ apow,
                                  const float* __restrict__ c1,
                                  const float* __restrict__ c2,
                                  const float* __restrict__ c3,
                                  const float* __restrict__ c4,
                                  const float* __restrict__ a1,
                                  const float* __restrict__ a2,
                                  const float* __restrict__ a3,
                                  const float* __restrict__ a4,
                                  float* __restrict__ consts) {
    if (threadIdx.x == 0) {
        auto sp = [](float x) { return log1pf(expf(x)); };
        float c1p = sp(*c1), c2p = sp(*c2), c3p = sp(*c3), c4p = sp(*c4);
        float inv = 1.0f / (c1p + c2p + c3p + c4p);
        consts[0] = sp(*apow);
        consts[1] = sp(*adiv);
        consts[2] = c1p * inv; consts[3] = c2p * inv;
        consts[4] = c3p * inv; consts[5] = c4p * inv;
        consts[6] = sp(*a1); consts[7] = sp(*a2);
        consts[8] = sp(*a3); consts[9] = sp(*a4);
    }
}

// ---------------------------------------------------------------------------
// zb[i] = (u8)Zf[i] — 500 KB gather table (L2-resident)
// ---------------------------------------------------------------------------
__global__ void zbl_pack_kernel(const float* __restrict__ Zf,
                                unsigned char* __restrict__ zb, int N) {
    int i = blockIdx.x * blockDim.x + threadIdx.x;
    if (i < N) zb[i] = (unsigned char)(Zf[i] + 0.5f);
}

// ---------------------------------------------------------------------------
// Phase A: per-chunk counting sort. Records are 4 B: [idx_local:16|f16:16].
// idx_i held in registers across the scan; zb[i] gathered in pass 1 so its
// latency hides under the histogram+scan barrier (packed 4 B/quad to keep
// VGPR <= 64); LDS stage + coalesced nontemporal dwordx4 flush (scattered
// global stores were a measured 2x-writeback regression).
// ---------------------------------------------------------------------------
__global__ void __launch_bounds__(ABLK)
zbl_phaseA(const int* __restrict__ idx_i, const int* __restrict__ idx_j,
           const float* __restrict__ rij, const float* __restrict__ cut,
           const unsigned char* __restrict__ zb,
           const float* __restrict__ consts,
           unsigned* __restrict__ recs, unsigned short* __restrict__ starts,
           int P, int NB, int nchunks) {
    __shared__ unsigned hist[NBMAX];
    __shared__ unsigned cursor[NBMAX];
    __shared__ unsigned wsum[NW_SCAN];
    __shared__ unsigned stage[CHUNK];     // 32 KB

    const int t = threadIdx.x;
    const int c = blockIdx.x;
    const int base = c * CHUNK;
    const int cnt = min(base + CHUNK, P) - base;
    const int n4 = cnt >> 2;

    for (int b = t; b < NBMAX; b += ABLK) hist[b] = 0;
    __syncthreads();

    // ---- pass 1: idx_i into registers; zb[i] gathers issued here so their
    // latency is covered by the histogram + scan phase.
    const v4i* ii4 = reinterpret_cast<const v4i*>(idx_i + base);
    const bool p0 = t < n4;
    const bool p1 = ABLK + t < n4;
    const bool p2 = 2 * ABLK + t < n4;
    const bool p3 = 3 * ABLK + t < n4;
    v4i ii0{}, ii1{}, ii2{}, ii3{};
    if (p0) ii0 = __builtin_nontemporal_load(ii4 + t);
    if (p1) ii1 = __builtin_nontemporal_load(ii4 + ABLK + t);
    if (p2) ii2 = __builtin_nontemporal_load(ii4 + 2 * ABLK + t);
    if (p3) ii3 = __builtin_nontemporal_load(ii4 + 3 * ABLK + t);

    auto packb = [&](v4i ii) -> unsigned {
        return (unsigned)zb[ii[0]] | ((unsigned)zb[ii[1]] << 8)
             | ((unsigned)zb[ii[2]] << 16) | ((unsigned)zb[ii[3]] << 24);
    };
    unsigned bp0 = 0, bp1 = 0, bp2 = 0, bp3 = 0;
    if (p0) bp0 = packb(ii0);
    if (p1) bp1 = packb(ii1);
    if (p2) bp2 = packb(ii2);
    if (p3) bp3 = packb(ii3);

    auto hist4 = [&](v4i ii) {
        atomicAdd(&hist[(unsigned)ii[0] >> APB_SHIFT], 1u);
        atomicAdd(&hist[(unsigned)ii[1] >> APB_SHIFT], 1u);
        atomicAdd(&hist[(unsigned)ii[2] >> APB_SHIFT], 1u);
        atomicAdd(&hist[(unsigned)ii[3] >> APB_SHIFT], 1u);
    };
    if (p0) hist4(ii0);
    if (p1) hist4(ii1);
    if (p2) hist4(ii2);
    if (p3) hist4(ii3);
    for (int p = n4 * 4 + t; p < cnt; p += ABLK)
        atomicAdd(&hist[(unsigned)idx_i[base + p] >> APB_SHIFT], 1u);
    __syncthreads();

    // ---- shuffle-based inclusive scan (2 barriers)
    unsigned hv = (t < NBMAX) ? hist[t] : 0u;
    unsigned v = hv;
#pragma unroll
    for (int off = 1; off < 64; off <<= 1) {
        unsigned n = __shfl_up(v, off, 64);
        if ((t & 63) >= off) v += n;
    }
    if (t < NBMAX && (t & 63) == 63) wsum[t >> 6] = v;
    __syncthreads();
    if (t < NBMAX) {
        unsigned pre = 0;
#pragma unroll
        for (int w = 0; w < NW_SCAN - 1; ++w)
            if (w < (t >> 6)) pre += wsum[w];
        unsigned inc = v + pre;           // inclusive scan of hist
        cursor[t] = inc - hv;             // exclusive base
        // transposed starts: row b = start of bucket b in chunk c
        if (t < NB)
            starts[(size_t)(t + 1) * nchunks + c] = (unsigned short)inc;
    }
    if (t == 0) starts[c] = 0;
    __syncthreads();                      // cursor visible to all waves

    // ---- pass 2: compute + rank + LDS stage
    const float sp_apow = consts[0], sp_adiv = consts[1];
    const float c1n = consts[2], c2n = consts[3], c3n = consts[4], c4n = consts[5];
    const float a1 = consts[6], a2 = consts[7], a3 = consts[8], a4 = consts[9];

    auto process = [&](int i, unsigned bi, unsigned bj, float r, float cu) {
        float fi = (float)bi, fj = (float)bj;
        float zi = __expf(sp_apow * __logf(fi));
        float zj = __expf(sp_apow * __logf(fj));
        float ar = (zi + zj) * sp_adiv * r;
        float f = c1n * __expf(-a1 * ar) + c2n * __expf(-a2 * ar)
                + c3n * __expf(-a3 * ar) + c4n * __expf(-a4 * ar);
        float contrib = KEHALF * f * cu * fi * fj * __builtin_amdgcn_rcpf(r);
        unsigned b = (unsigned)i >> APB_SHIFT;
        unsigned rank = atomicAdd(&cursor[b], 1u);
        stage[rank] = (((unsigned)i & (APB - 1)) << 16)
                    | (unsigned)__half_as_ushort(__float2half_rn(contrib));
    };

    const v4i* jj4 = reinterpret_cast<const v4i*>(idx_j + base);
    const v4f* rr4 = reinterpret_cast<const v4f*>(rij + base);
    const v4f* cc4 = reinterpret_cast<const v4f*>(cut + base);
    auto group = [&](v4i ii, unsigned bp, int q) {
        v4i jj = __builtin_nontemporal_load(jj4 + q);
        v4f rr = __builtin_nontemporal_load(rr4 + q);
        v4f cc = __builtin_nontemporal_load(cc4 + q);
#pragma unroll
        for (int k = 0; k < 4; ++k)
            process(ii[k], (bp >> (8 * k)) & 0xffu, zb[jj[k]], rr[k], cc[k]);
    };
    if (p0) group(ii0, bp0, t);
    if (p1) group(ii1, bp1, ABLK + t);
    if (p2) group(ii2, bp2, 2 * ABLK + t);
    if (p3) group(ii3, bp3, 3 * ABLK + t);
    for (int p = n4 * 4 + t; p < cnt; p += ABLK) {
        int i = idx_i[base + p];
        process(i, zb[i], zb[idx_j[base + p]], rij[base + p], cut[base + p]);
    }
    __syncthreads();

    // ---- flush: coalesced 16 B/lane streaming stores (full chunk; pad
    // entries beyond cnt are garbage but never referenced by starts)
    {
        const v4u* src = reinterpret_cast<const v4u*>(stage);
        v4u* dst = reinterpret_cast<v4u*>(recs + (size_t)base);
        for (int k = t; k < CHUNK / 4; k += ABLK)
            __builtin_nontemporal_store(src[k], dst + k);
    }
}

// ---------------------------------------------------------------------------
// Phase B: grid (NB, SPLIT). Each block owns one bucket x one chunk slice;
// transposed starts -> contiguous row reads; half-wave per chunk segment;
// ds-atomic into 8 KB tile; merge into pre-zeroed out via f32 atomics.
// ---------------------------------------------------------------------------
__global__ void __launch_bounds__(BBLK)
zbl_phaseB(const unsigned* __restrict__ recs,
           const unsigned short* __restrict__ starts,
           float* __restrict__ out, int N, int NB, int nchunks, int cpb) {
    __shared__ float acc[APB];                 // 8 KB
    __shared__ unsigned short s0s[CTILE];      // 2 KB
    __shared__ unsigned short s1s[CTILE];      // 2 KB
    const int t = threadIdx.x;
    const int b = blockIdx.x;
    const int c0 = blockIdx.y * cpb;
    const int c1e = min(c0 + cpb, nchunks);
    for (int i = t; i < APB; i += BBLK) acc[i] = 0.f;

    const unsigned short* s0row = starts + (size_t)b * nchunks;
    const unsigned short* s1row = starts + (size_t)(b + 1) * nchunks;
    const int hw = t >> 5, hl = t & 31, nhw = BBLK / 32;

    for (int cb = c0; cb < c1e; cb += CTILE) {
        const int ce = min(cb + CTILE, c1e);
        __syncthreads();
        for (int c = cb + t; c < ce; c += BBLK) {
            s0s[c - cb] = s0row[c];
            s1s[c - cb] = s1row[c];
        }
        __syncthreads();
        for (int c = cb + hw; c < ce; c += nhw) {
            unsigned s0 = s0s[c - cb], s1 = s1s[c - cb];
            const unsigned* seg = recs + (size_t)c * CHUNK;
            for (unsigned u = s0 + hl; u < s1; u += 32) {
                unsigned rec = __builtin_nontemporal_load(seg + u);
                float v = __half2float(__ushort_as_half((unsigned short)(rec & 0xffffu)));
                atomicAdd(&acc[rec >> 16], v);
            }
        }
    }
    __syncthreads();
    const int abase = b << APB_SHIFT;
    for (int i = t; i < APB; i += BBLK) {
        int g = abase + i;
        if (g < N) atomicAdd(&out[g], acc[i]);
    }
}

// ---------------------------------------------------------------------------
// Fallback (tiny ws): direct device-scope atomics.
// ---------------------------------------------------------------------------
__global__ void __launch_bounds__(256)
zbl_pair_fallback(const v4f* __restrict__ rij4, const v4f* __restrict__ cut4,
                  const v4i* __restrict__ ii4, const v4i* __restrict__ jj4,
                  const float* __restrict__ Zf, const float* __restrict__ consts,
                  float* __restrict__ out, int P4) {
    int t = blockIdx.x * blockDim.x + threadIdx.x;
    if (t >= P4) return;
    const float sp_apow = consts[0], sp_adiv = consts[1];
    const float c1n = consts[2], c2n = consts[3], c3n = consts[4], c4n = consts[5];
    const float a1 = consts[6], a2 = consts[7], a3 = consts[8], a4 = consts[9];
    v4f rr = rij4[t]; v4f cc = cut4[t]; v4i ii = ii4[t]; v4i jj = jj4[t];
#pragma unroll
    for (int k = 0; k < 4; ++k) {
        int i = ii[k], j = jj[k];
        float zfi = Zf[i], zfj = Zf[j];
        float zi = __expf(sp_apow * __logf(zfi));
        float zj = __expf(sp_apow * __logf(zfj));
        float a = (zi + zj) * sp_adiv;
        float ar = a * rr[k];
        float f = c1n * __expf(-a1 * ar) + c2n * __expf(-a2 * ar)
                + c3n * __expf(-a3 * ar) + c4n * __expf(-a4 * ar);
        atomicAdd(&out[i],
                  KEHALF * f * cc[k] * zfi * zfj * __builtin_amdgcn_rcpf(rr[k]));
    }
}

// ---------------------------------------------------------------------------
extern "C" void kernel_launch(void* const* d_in, const int* in_sizes, int n_in,
                              void* d_out, int out_size, void* d_ws, size_t ws_size,
                              hipStream_t stream) {
    // 0:N 1:Zf 2:rij 3:cutoff 4:idx_i 5:idx_j 6:adiv 7:apow 8..11:c 12..15:a
    const float* Zf = (const float*)d_in[1];
    const float* rij = (const float*)d_in[2];
    const float* cut = (const float*)d_in[3];
    const int* idx_i = (const int*)d_in[4];
    const int* idx_j = (const int*)d_in[5];
    const int N = in_sizes[1];
    const int P = in_sizes[2];
    float* out = (float*)d_out;

    const int NB = (N + APB - 1) / APB;
    const int nchunks = (P + CHUNK - 1) / CHUNK;

    // ws layout: recs[nchunks*CHUNK] u32 | starts[(NB+1)*nchunks] u16 |
    //            consts[16] f32 | zb[N] u8
    size_t recs_bytes = (size_t)nchunks * CHUNK * 4;
    size_t starts_bytes = (size_t)(NB + 1) * nchunks * 2;
    size_t consts_off = (recs_bytes + starts_bytes + 255) & ~(size_t)255;
    size_t zb_off = consts_off + 16 * 4;
    size_t need = zb_off + (size_t)N + 64;

    if (NB <= NBMAX && ws_size >= need) {
        unsigned* recs = (unsigned*)d_ws;
        unsigned short* starts = (unsigned short*)((char*)d_ws + recs_bytes);
        float* consts = (float*)((char*)d_ws + consts_off);
        unsigned char* zb = (unsigned char*)((char*)d_ws + zb_off);

        zbl_tables_kernel<<<1, 64, 0, stream>>>(
            (const float*)d_in[6], (const float*)d_in[7],
            (const float*)d_in[8], (const float*)d_in[9],
            (const float*)d_in[10], (const float*)d_in[11],
            (const float*)d_in[12], (const float*)d_in[13],
            (const float*)d_in[14], (const float*)d_in[15], consts);

        zbl_pack_kernel<<<(N + 255) / 256, 256, 0, stream>>>(Zf, zb, N);

        hipMemsetAsync(out, 0, (size_t)out_size * sizeof(float), stream);

        zbl_phaseA<<<nchunks, ABLK, 0, stream>>>(
            idx_i, idx_j, rij, cut, zb, consts, recs, starts, P, NB, nchunks);

        int SPLIT = (2048 + NB - 1) / NB;
        if (SPLIT < 1) SPLIT = 1;
        if (SPLIT > 16) SPLIT = 16;
        const int cpb = (nchunks + SPLIT - 1) / SPLIT;
        dim3 gridB(NB, SPLIT);
        zbl_phaseB<<<gridB, BBLK, 0, stream>>>(recs, starts, out, N, NB,
                                               nchunks, cpb);
    } else {
        float* consts = (float*)d_ws;
        hipMemsetAsync(out, 0, (size_t)out_size * sizeof(float), stream);
        zbl_tables_kernel<<<1, 64, 0, stream>>>(
            (const float*)d_in[6], (const float*)d_in[7],
            (const float*)d_in[8], (const float*)d_in[9],
            (const float*)d_in[10], (const float*)d_in[11],
            (const float*)d_in[12], (const float*)d_in[13],
            (const float*)d_in[14], (const float*)d_in[15], consts);
        zbl_pair_fallback<<<(P / 4 + 255) / 256, 256, 0, stream>>>(
            (const v4f*)rij, (const v4f*)cut, (const v4i*)idx_i,
            (const v4i*)idx_j, Zf, consts, out, P / 4);
    }
}

// Round 3
// 438.255 us; speedup vs baseline: 1.2382x; 1.0353x over previous
//
#include <hip/hip_runtime.h>
#include <hip/hip_fp16.h>

static constexpr float KEHALF = 7.199822675975274f; // 14.399645351950548 / 2
static constexpr int APB = 2048;          // atoms per bucket (8 KB acc tile)
static constexpr int APB_SHIFT = 11;
static constexpr int NBMAX = 256;         // scan width (pow2); NB <= this
static constexpr int CHUNK = 8192;        // pairs per Phase-A block (32 KB stage)
static constexpr int ABLK = 512;          // Phase-A block size
static constexpr int BBLK = 1024;         // Phase-B block size
static constexpr int CTILE = 1024;        // Phase-B chunk-range staging tile
static constexpr int NW_SCAN = NBMAX / 64;

typedef float v4f __attribute__((ext_vector_type(4)));
typedef int   v4i __attribute__((ext_vector_type(4)));
typedef unsigned v4u __attribute__((ext_vector_type(4)));

// ---------------------------------------------------------------------------
// consts [0]=sp(apow) [1]=sp(adiv) [2..5]=c1n..c4n [6..9]=sp(a1..a4)
// ---------------------------------------------------------------------------
__device__ __forceinline__ void compute_consts(
        const float* adiv, const float* apow,
        const float* c1, const float* c2, const float* c3, const float* c4,
        const float* a1, const float* a2, const float* a3, const float* a4,
        float* consts) {
    auto sp = [](float x) { return log1pf(expf(x)); };
    float c1p = sp(*c1), c2p = sp(*c2), c3p = sp(*c3), c4p = sp(*c4);
    float inv = 1.0f / (c1p + c2p + c3p + c4p);
    consts[0] = sp(*apow);
    consts[1] = sp(*adiv);
    consts[2] = c1p * inv; consts[3] = c2p * inv;
    consts[4] = c3p * inv; consts[5] = c4p * inv;
    consts[6] = sp(*a1); consts[7] = sp(*a2);
    consts[8] = sp(*a3); consts[9] = sp(*a4);
}

__global__ void zbl_tables_kernel(const float* __restrict__ adiv,
                                  const float* __restrict__ apow,
                                  const float* __restrict__ c1,
                                  const float* __restrict__ c2,
                                  const float* __restrict__ c3,
                                  const float* __restrict__ c4,
                                  const float* __restrict__ a1,
                                  const float* __restrict__ a2,
                                  const float* __restrict__ a3,
                                  const float* __restrict__ a4,
                                  float* __restrict__ consts) {
    if (threadIdx.x == 0)
        compute_consts(adiv, apow, c1, c2, c3, c4, a1, a2, a3, a4, consts);
}

// ---------------------------------------------------------------------------
// prep: zb pack + out zero + consts (one dispatch instead of three)
// ---------------------------------------------------------------------------
__global__ void zbl_prep(const float* __restrict__ Zf,
                         unsigned char* __restrict__ zb,
                         float* __restrict__ out, int N,
                         const float* __restrict__ adiv,
                         const float* __restrict__ apow,
                         const float* __restrict__ c1,
                         const float* __restrict__ c2,
                         const float* __restrict__ c3,
                         const float* __restrict__ c4,
                         const float* __restrict__ a1,
                         const float* __restrict__ a2,
                         const float* __restrict__ a3,
                         const float* __restrict__ a4,
                         float* __restrict__ consts) {
    int i = blockIdx.x * blockDim.x + threadIdx.x;
    if (i < N) {
        zb[i] = (unsigned char)(Zf[i] + 0.5f);
        out[i] = 0.0f;
    }
    if (blockIdx.x == 0 && threadIdx.x == 0)
        compute_consts(adiv, apow, c1, c2, c3, c4, a1, a2, a3, a4, consts);
}

// ---------------------------------------------------------------------------
// Phase A: per-chunk counting sort. Records are 4 B: [idx_local:16|f16:16].
// All 32M random zb gathers (i AND j sides) issue in pass 1, hidden under
// the histogram+scan barriers; pass 2 is pure {coalesced load, LDS LUT,
// VALU} with no global-latency link in its dependency chain. z^p comes from
// a per-block 96-entry LDS LUT (2 transcendentals once vs 4 per pair).
// ---------------------------------------------------------------------------
__global__ void __launch_bounds__(ABLK)
zbl_phaseA(const int* __restrict__ idx_i, const int* __restrict__ idx_j,
           const float* __restrict__ rij, const float* __restrict__ cut,
           const unsigned char* __restrict__ zb,
           const float* __restrict__ consts,
           unsigned* __restrict__ recs, unsigned short* __restrict__ starts,
           int P, int NB, int nchunks) {
    __shared__ unsigned hist[NBMAX];
    __shared__ unsigned cursor[NBMAX];
    __shared__ unsigned wsum[NW_SCAN];
    __shared__ float lA[96];              // lA[z] = sp(adiv) * z^sp(apow)
    __shared__ unsigned stage[CHUNK];     // 32 KB

    const int t = threadIdx.x;
    const int c = blockIdx.x;
    const int base = c * CHUNK;
    const int cnt = min(base + CHUNK, P) - base;
    const int n4 = cnt >> 2;

    for (int b = t; b < NBMAX; b += ABLK) hist[b] = 0;
    if (t < 96)
        lA[t] = (t == 0) ? 0.0f
                         : consts[1] * __expf(consts[0] * __logf((float)t));
    __syncthreads();

    // ---- pass 1: idx into registers; ALL zb gathers issued here so their
    // latency hides under histogram + scan.
    const v4i* ii4 = reinterpret_cast<const v4i*>(idx_i + base);
    const v4i* jj4 = reinterpret_cast<const v4i*>(idx_j + base);
    const bool p0 = t < n4;
    const bool p1 = ABLK + t < n4;
    const bool p2 = 2 * ABLK + t < n4;
    const bool p3 = 3 * ABLK + t < n4;
    v4i ii0{}, ii1{}, ii2{}, ii3{}, jj0{}, jj1{}, jj2{}, jj3{};
    if (p0) { ii0 = ii4[t];            jj0 = jj4[t]; }
    if (p1) { ii1 = ii4[ABLK + t];     jj1 = jj4[ABLK + t]; }
    if (p2) { ii2 = ii4[2 * ABLK + t]; jj2 = jj4[2 * ABLK + t]; }
    if (p3) { ii3 = ii4[3 * ABLK + t]; jj3 = jj4[3 * ABLK + t]; }

    auto packb = [&](v4i ix) -> unsigned {
        return (unsigned)zb[ix[0]] | ((unsigned)zb[ix[1]] << 8)
             | ((unsigned)zb[ix[2]] << 16) | ((unsigned)zb[ix[3]] << 24);
    };
    unsigned bpi0 = 0, bpi1 = 0, bpi2 = 0, bpi3 = 0;
    unsigned bpj0 = 0, bpj1 = 0, bpj2 = 0, bpj3 = 0;
    if (p0) { bpi0 = packb(ii0); bpj0 = packb(jj0); }
    if (p1) { bpi1 = packb(ii1); bpj1 = packb(jj1); }
    if (p2) { bpi2 = packb(ii2); bpj2 = packb(jj2); }
    if (p3) { bpi3 = packb(ii3); bpj3 = packb(jj3); }

    auto hist4 = [&](v4i ii) {
        atomicAdd(&hist[(unsigned)ii[0] >> APB_SHIFT], 1u);
        atomicAdd(&hist[(unsigned)ii[1] >> APB_SHIFT], 1u);
        atomicAdd(&hist[(unsigned)ii[2] >> APB_SHIFT], 1u);
        atomicAdd(&hist[(unsigned)ii[3] >> APB_SHIFT], 1u);
    };
    if (p0) hist4(ii0);
    if (p1) hist4(ii1);
    if (p2) hist4(ii2);
    if (p3) hist4(ii3);
    for (int p = n4 * 4 + t; p < cnt; p += ABLK)
        atomicAdd(&hist[(unsigned)idx_i[base + p] >> APB_SHIFT], 1u);
    __syncthreads();

    // ---- shuffle-based inclusive scan (2 barriers)
    unsigned hv = (t < NBMAX) ? hist[t] : 0u;
    unsigned v = hv;
#pragma unroll
    for (int off = 1; off < 64; off <<= 1) {
        unsigned n = __shfl_up(v, off, 64);
        if ((t & 63) >= off) v += n;
    }
    if (t < NBMAX && (t & 63) == 63) wsum[t >> 6] = v;
    __syncthreads();
    if (t < NBMAX) {
        unsigned pre = 0;
#pragma unroll
        for (int w = 0; w < NW_SCAN - 1; ++w)
            if (w < (t >> 6)) pre += wsum[w];
        unsigned inc = v + pre;           // inclusive scan of hist
        cursor[t] = inc - hv;             // exclusive base
        // transposed starts: row b = start of bucket b per chunk
        if (t < NB)
            starts[(size_t)(t + 1) * nchunks + c] = (unsigned short)inc;
    }
    if (t == 0) starts[c] = 0;
    __syncthreads();                      // cursor + lA visible to all waves

    // ---- pass 2: pure compute + rank + LDS stage (no global latency)
    const float c1n = consts[2], c2n = consts[3], c3n = consts[4], c4n = consts[5];
    const float a1 = consts[6], a2 = consts[7], a3 = consts[8], a4 = consts[9];

    auto process = [&](int i, unsigned bi, unsigned bj, float r, float cu) {
        float ar = (lA[bi] + lA[bj]) * r;
        float f = c1n * __expf(-a1 * ar) + c2n * __expf(-a2 * ar)
                + c3n * __expf(-a3 * ar) + c4n * __expf(-a4 * ar);
        float contrib = KEHALF * f * cu * (float)bi * (float)bj *
                        __builtin_amdgcn_rcpf(r);
        unsigned b = (unsigned)i >> APB_SHIFT;
        unsigned rank = atomicAdd(&cursor[b], 1u);
        stage[rank] = (((unsigned)i & (APB - 1)) << 16)
                    | (unsigned)__half_as_ushort(__float2half_rn(contrib));
    };

    const v4f* rr4 = reinterpret_cast<const v4f*>(rij + base);
    const v4f* cc4 = reinterpret_cast<const v4f*>(cut + base);
    auto group = [&](v4i ii, unsigned bpi, unsigned bpj, int q) {
        v4f rr = rr4[q];
        v4f cc = cc4[q];
#pragma unroll
        for (int k = 0; k < 4; ++k)
            process(ii[k], (bpi >> (8 * k)) & 0xffu, (bpj >> (8 * k)) & 0xffu,
                    rr[k], cc[k]);
    };
    if (p0) group(ii0, bpi0, bpj0, t);
    if (p1) group(ii1, bpi1, bpj1, ABLK + t);
    if (p2) group(ii2, bpi2, bpj2, 2 * ABLK + t);
    if (p3) group(ii3, bpi3, bpj3, 3 * ABLK + t);
    for (int p = n4 * 4 + t; p < cnt; p += ABLK) {
        int i = idx_i[base + p];
        process(i, zb[i], zb[idx_j[base + p]], rij[base + p], cut[base + p]);
    }
    __syncthreads();

    // ---- flush: coalesced 16 B/lane stores (regular, so recs stay L3-hot
    // for phaseB; pad entries beyond cnt are garbage but never referenced)
    {
        const v4u* src = reinterpret_cast<const v4u*>(stage);
        v4u* dst = reinterpret_cast<v4u*>(recs + (size_t)base);
        for (int k = t; k < CHUNK / 4; k += ABLK)
            dst[k] = src[k];
    }
}

// ---------------------------------------------------------------------------
// Phase B: grid (NB, SPLIT). Each block owns one bucket x one chunk slice;
// transposed starts -> contiguous row reads; half-wave per chunk segment;
// ds-atomic into 8 KB tile; merge into pre-zeroed out via f32 atomics.
// ---------------------------------------------------------------------------
__global__ void __launch_bounds__(BBLK)
zbl_phaseB(const unsigned* __restrict__ recs,
           const unsigned short* __restrict__ starts,
           float* __restrict__ out, int N, int NB, int nchunks, int cpb) {
    __shared__ float acc[APB];                 // 8 KB
    __shared__ unsigned short s0s[CTILE];      // 2 KB
    __shared__ unsigned short s1s[CTILE];      // 2 KB
    const int t = threadIdx.x;
    const int b = blockIdx.x;
    const int c0 = blockIdx.y * cpb;
    const int c1e = min(c0 + cpb, nchunks);
    for (int i = t; i < APB; i += BBLK) acc[i] = 0.f;

    const unsigned short* s0row = starts + (size_t)b * nchunks;
    const unsigned short* s1row = starts + (size_t)(b + 1) * nchunks;
    const int hw = t >> 5, hl = t & 31, nhw = BBLK / 32;

    for (int cb = c0; cb < c1e; cb += CTILE) {
        const int ce = min(cb + CTILE, c1e);
        __syncthreads();
        for (int c = cb + t; c < ce; c += BBLK) {
            s0s[c - cb] = s0row[c];
            s1s[c - cb] = s1row[c];
        }
        __syncthreads();
        for (int c = cb + hw; c < ce; c += nhw) {
            unsigned s0 = s0s[c - cb], s1 = s1s[c - cb];
            const unsigned* seg = recs + (size_t)c * CHUNK;
            for (unsigned u = s0 + hl; u < s1; u += 32) {
                unsigned rec = seg[u];
                float v = __half2float(__ushort_as_half((unsigned short)(rec & 0xffffu)));
                atomicAdd(&acc[rec >> 16], v);
            }
        }
    }
    __syncthreads();
    const int abase = b << APB_SHIFT;
    for (int i = t; i < APB; i += BBLK) {
        int g = abase + i;
        if (g < N) atomicAdd(&out[g], acc[i]);
    }
}

// ---------------------------------------------------------------------------
// Fallback (tiny ws): direct device-scope atomics.
// ---------------------------------------------------------------------------
__global__ void __launch_bounds__(256)
zbl_pair_fallback(const v4f* __restrict__ rij4, const v4f* __restrict__ cut4,
                  const v4i* __restrict__ ii4, const v4i* __restrict__ jj4,
                  const float* __restrict__ Zf, const float* __restrict__ consts,
                  float* __restrict__ out, int P4) {
    int t = blockIdx.x * blockDim.x + threadIdx.x;
    if (t >= P4) return;
    const float sp_apow = consts[0], sp_adiv = consts[1];
    const float c1n = consts[2], c2n = consts[3], c3n = consts[4], c4n = consts[5];
    const float a1 = consts[6], a2 = consts[7], a3 = consts[8], a4 = consts[9];
    v4f rr = rij4[t]; v4f cc = cut4[t]; v4i ii = ii4[t]; v4i jj = jj4[t];
#pragma unroll
    for (int k = 0; k < 4; ++k) {
        int i = ii[k], j = jj[k];
        float zfi = Zf[i], zfj = Zf[j];
        float zi = __expf(sp_apow * __logf(zfi));
        float zj = __expf(sp_apow * __logf(zfj));
        float a = (zi + zj) * sp_adiv;
        float ar = a * rr[k];
        float f = c1n * __expf(-a1 * ar) + c2n * __expf(-a2 * ar)
                + c3n * __expf(-a3 * ar) + c4n * __expf(-a4 * ar);
        atomicAdd(&out[i],
                  KEHALF * f * cc[k] * zfi * zfj * __builtin_amdgcn_rcpf(rr[k]));
    }
}

// ---------------------------------------------------------------------------
extern "C" void kernel_launch(void* const* d_in, const int* in_sizes, int n_in,
                              void* d_out, int out_size, void* d_ws, size_t ws_size,
                              hipStream_t stream) {
    // 0:N 1:Zf 2:rij 3:cutoff 4:idx_i 5:idx_j 6:adiv 7:apow 8..11:c 12..15:a
    const float* Zf = (const float*)d_in[1];
    const float* rij = (const float*)d_in[2];
    const float* cut = (const float*)d_in[3];
    const int* idx_i = (const int*)d_in[4];
    const int* idx_j = (const int*)d_in[5];
    const int N = in_sizes[1];
    const int P = in_sizes[2];
    float* out = (float*)d_out;

    const int NB = (N + APB - 1) / APB;
    const int nchunks = (P + CHUNK - 1) / CHUNK;

    // ws layout: recs[nchunks*CHUNK] u32 | starts[(NB+1)*nchunks] u16 |
    //            consts[16] f32 | zb[N] u8
    size_t recs_bytes = (size_t)nchunks * CHUNK * 4;
    size_t starts_bytes = (size_t)(NB + 1) * nchunks * 2;
    size_t consts_off = (recs_bytes + starts_bytes + 255) & ~(size_t)255;
    size_t zb_off = consts_off + 16 * 4;
    size_t need = zb_off + (size_t)N + 64;

    if (NB <= NBMAX && ws_size >= need) {
        unsigned* recs = (unsigned*)d_ws;
        unsigned short* starts = (unsigned short*)((char*)d_ws + recs_bytes);
        float* consts = (float*)((char*)d_ws + consts_off);
        unsigned char* zb = (unsigned char*)((char*)d_ws + zb_off);

        zbl_prep<<<(N + 255) / 256, 256, 0, stream>>>(
            Zf, zb, out, N,
            (const float*)d_in[6], (const float*)d_in[7],
            (const float*)d_in[8], (const float*)d_in[9],
            (const float*)d_in[10], (const float*)d_in[11],
            (const float*)d_in[12], (const float*)d_in[13],
            (const float*)d_in[14], (const float*)d_in[15], consts);

        zbl_phaseA<<<nchunks, ABLK, 0, stream>>>(
            idx_i, idx_j, rij, cut, zb, consts, recs, starts, P, NB, nchunks);

        int SPLIT = 4096 / (NB > 0 ? NB : 1);
        if (SPLIT < 1) SPLIT = 1;
        if (SPLIT > 16) SPLIT = 16;
        const int cpb = (nchunks + SPLIT - 1) / SPLIT;
        dim3 gridB(NB, SPLIT);
        zbl_phaseB<<<gridB, BBLK, 0, stream>>>(recs, starts, out, N, NB,
                                               nchunks, cpb);
    } else {
        float* consts = (float*)d_ws;
        hipMemsetAsync(out, 0, (size_t)out_size * sizeof(float), stream);
        zbl_tables_kernel<<<1, 64, 0, stream>>>(
            (const float*)d_in[6], (const float*)d_in[7],
            (const float*)d_in[8], (const float*)d_in[9],
            (const float*)d_in[10], (const float*)d_in[11],
            (const float*)d_in[12], (const float*)d_in[13],
            (const float*)d_in[14], (const float*)d_in[15], consts);
        zbl_pair_fallback<<<(P / 4 + 255) / 256, 256, 0, stream>>>(
            (const v4f*)rij, (const v4f*)cut, (const v4i*)idx_i,
            (const v4i*)idx_j, Zf, consts, out, P / 4);
    }
}